// Round 5
// baseline (80.737 us; speedup 1.0000x reference)
//
#include <hip/hip_runtime.h>
#include <hip/hip_bf16.h>

#define T_LEN 4096
#define NLAG  6
#define PADW  768              // NLAG*128
#define ROWW  4992             // PADW + T_LEN + 128 tail pad
#define NCH   624              // ROWW/8

typedef __attribute__((ext_vector_type(8))) short short8;
typedef __attribute__((ext_vector_type(4))) float f32x4;

static __device__ __forceinline__ unsigned short f2bf(float f) {
  __hip_bfloat16 h = __float2bfloat16(f);
  return *reinterpret_cast<unsigned short*>(&h);
}

// One kernel: phase A (kt build + u->bf16 pad) -> grid barrier -> phase B (GEMM).
// Grid is exactly 256 blocks x 96KB LDS = 1 block/CU on 256 CUs: all co-resident,
// so the atomic spin barrier cannot deadlock.
__global__ __launch_bounds__(256) void ssm_fused(
    const float* __restrict__ u, const float* __restrict__ rho,
    const float* __restrict__ theta, const float* __restrict__ br,
    const float* __restrict__ bi, const float* __restrict__ cr,
    const float* __restrict__ ci, unsigned short* __restrict__ kt,
    unsigned short* __restrict__ up, int* __restrict__ ctr,
    float* __restrict__ out) {
  __shared__ __align__(16) unsigned short lds[3][2][8192];  // 3 bufs x {A,B} x 16KB
  const int tid = threadIdx.x;
  const int bid = blockIdx.x;
  const int lane = tid & 63;
  const int w = tid >> 6;

  // ---------- Phase A1: kt[j][r][s] = k_{j*128+r-s}, one lag d per wave ----------
  if (bid < 224) {                        // 896 waves cover d in [-127, 768]
    const int d = bid * 4 + w - 127;
    float v = 0.f;
    if (d >= 0) {                         // wave-uniform branch
      const float logr = -log1pf(expf(rho[lane]));
      const float rd = expf((float)d * logr);
      const float ang = theta[lane] * (float)d;
      const float brv = br[lane], biv = bi[lane];
      const float crv = cr[lane], civ = ci[lane];
      const float gr = crv * brv + civ * biv;
      const float gi = crv * biv - civ * brv;
      v = rd * (gr * cosf(ang) - gi * sinf(ang));
#pragma unroll
      for (int off = 1; off < 64; off <<= 1) v += __shfl_xor(v, off);
    }
    const unsigned short kv = f2bf(v);
#pragma unroll
    for (int j = 0; j < NLAG; ++j) {
      const int delta = d - j * 128;      // r - s on tile j
      if (delta >= -127 && delta <= 63) {
        const int s = lane - delta;
        if (s >= 0 && s < 128) kt[(j * 64 + lane) * 128 + s] = kv;
      }
    }
  }

  // ---------- Phase A2: block bid converts u row bid to zero-padded bf16 ----------
  {
    const float* ur = u + (size_t)bid * T_LEN;
    unsigned short* upr = up + (size_t)bid * ROWW;
    for (int c = tid; c < NCH; c += 256) {
      const int s0 = c * 8 - PADW;        // in-range chunks are exactly [96, 607]
      short8 o = {};
      if (s0 >= 0 && s0 + 8 <= T_LEN) {
        const float4 a = *reinterpret_cast<const float4*>(ur + s0);
        const float4 b = *reinterpret_cast<const float4*>(ur + s0 + 4);
        o[0] = (short)f2bf(a.x); o[1] = (short)f2bf(a.y);
        o[2] = (short)f2bf(a.z); o[3] = (short)f2bf(a.w);
        o[4] = (short)f2bf(b.x); o[5] = (short)f2bf(b.y);
        o[6] = (short)f2bf(b.z); o[7] = (short)f2bf(b.w);
      }
      *reinterpret_cast<short8*>(upr + c * 8) = o;
    }
  }

  // ---------- grid barrier (release stores -> arrival; acquire spin) ----------
  __threadfence();
  __syncthreads();
  if (tid == 0) {
    __hip_atomic_fetch_add(ctr, 1, __ATOMIC_RELEASE, __HIP_MEMORY_SCOPE_AGENT);
    while (__hip_atomic_load(ctr, __ATOMIC_ACQUIRE, __HIP_MEMORY_SCOPE_AGENT) <
           (int)gridDim.x) {
      __builtin_amdgcn_s_sleep(2);
    }
  }
  __syncthreads();
  __threadfence();

  // ---------- Phase B: banded Toeplitz GEMM (round-3 core, NLAG=6) ----------
  const int wm = (w >> 1) & 1, wn = w & 1;   // w in 0..3
  const int swz = (bid & 7) * 32 + (bid >> 3);   // bijective XCD swizzle (256%8==0)
  const int t0 = (swz & 63) * 64;
  const int b0 = (swz >> 6) * 64;
  const int lrow = lane >> 4;
  const int lc16 = lane & 15;

  f32x4 acc[2][2] = {};

#define STAGE(buf, j)                                                              \
  {                                                                                \
    const int sb_ = t0 + PADW - (j) * 128;                                         \
    _Pragma("unroll") for (int i_ = 0; i_ < 4; ++i_) {                             \
      const int ii_ = w * 4 + i_;                                                  \
      const int r_ = ii_ * 4 + lrow;                                               \
      const int le_ = (lc16 * 8) ^ ((r_ & 7) << 3);                                \
      __builtin_amdgcn_global_load_lds(                                            \
          (const __attribute__((address_space(1))) void*)(up +                     \
              (size_t)(b0 + r_) * ROWW + sb_ + le_),                               \
          (__attribute__((address_space(3))) void*)&lds[buf][0][ii_ * 512],        \
          16, 0, 0);                                                               \
      __builtin_amdgcn_global_load_lds(                                            \
          (const __attribute__((address_space(1))) void*)(kt + (j) * 8192 +        \
              r_ * 128 + le_),                                                     \
          (__attribute__((address_space(3))) void*)&lds[buf][1][ii_ * 512],        \
          16, 0, 0);                                                               \
    }                                                                              \
  }

  STAGE(0, 0);
  STAGE(1, 1);

#pragma unroll
  for (int j = 0; j < NLAG; ++j) {
    // own stage-j loads done (8 newer stay in flight); barrier makes it global
    if (j < NLAG - 1) asm volatile("s_waitcnt vmcnt(8)" ::: "memory");
    else              asm volatile("s_waitcnt vmcnt(0)" ::: "memory");
    asm volatile("s_barrier" ::: "memory");
    // stage j+2 into buf (j+2)%3 == (j-1)%3: last read at compute j-1, which
    // precedes barrier j in every wave's program order -> race-free.
    if (j + 2 < NLAG) STAGE((j + 2) % 3, j + 2);

    const unsigned short* A  = lds[j % 3][0];
    const unsigned short* Bt = lds[j % 3][1];
#pragma unroll
    for (int ks = 0; ks < 4; ++ks) {
      short8 af[2], bfr[2];
#pragma unroll
      for (int ft = 0; ft < 2; ++ft) {
        const int r = wm * 32 + ft * 16 + lc16;
        const int pe = (ks * 32 + lrow * 8) ^ ((r & 7) << 3);
        af[ft] = *reinterpret_cast<const short8*>(&A[r * 128 + pe]);
      }
#pragma unroll
      for (int fn = 0; fn < 2; ++fn) {
        const int r = wn * 32 + fn * 16 + lc16;
        const int pe = (ks * 32 + lrow * 8) ^ ((r & 7) << 3);
        bfr[fn] = *reinterpret_cast<const short8*>(&Bt[r * 128 + pe]);
      }
#pragma unroll
      for (int ft = 0; ft < 2; ++ft)
#pragma unroll
        for (int fn = 0; fn < 2; ++fn)
          acc[ft][fn] = __builtin_amdgcn_mfma_f32_16x16x32_bf16(
              af[ft], bfr[fn], acc[ft][fn], 0, 0, 0);
    }
  }

#pragma unroll
  for (int ft = 0; ft < 2; ++ft)
#pragma unroll
    for (int fn = 0; fn < 2; ++fn)
#pragma unroll
      for (int rg = 0; rg < 4; ++rg) {
        const int row = b0 + wm * 32 + ft * 16 + lrow * 4 + rg;
        const int col = t0 + wn * 32 + fn * 16 + lc16;
        out[(size_t)row * T_LEN + col] = acc[ft][fn][rg];
      }
#undef STAGE
}

extern "C" void kernel_launch(void* const* d_in, const int* in_sizes, int n_in,
                              void* d_out, int out_size, void* d_ws, size_t ws_size,
                              hipStream_t stream) {
  const float* u     = (const float*)d_in[0];
  const float* rho   = (const float*)d_in[1];
  const float* theta = (const float*)d_in[2];
  const float* br    = (const float*)d_in[3];
  const float* bi    = (const float*)d_in[4];
  const float* cr    = (const float*)d_in[5];
  const float* ci    = (const float*)d_in[6];
  float* out = (float*)d_out;

  char* ws = (char*)d_ws;
  int* ctr           = (int*)ws;                           // 4 B, re-zeroed per call
  unsigned short* kt = (unsigned short*)(ws + 1024);       // 6*64*128 bf16 = 96 KB
  unsigned short* up = (unsigned short*)(ws + 102400);     // 256*4992 bf16 = 2.44 MB

  hipMemsetAsync(ctr, 0, 4, stream);                       // graph-capturable
  ssm_fused<<<256, 256, 0, stream>>>(u, rho, theta, br, bi, cr, ci, kt, up, ctr, out);
}

// Round 6
// 32.279 us; speedup vs baseline: 2.5013x; 2.5013x over previous
//
#include <hip/hip_runtime.h>
#include <hip/hip_bf16.h>

#define T_LEN 4096
#define NLAG  6              // max lag 703; validated absmax 2.0 in round 5

typedef __attribute__((ext_vector_type(8))) short short8;
typedef __attribute__((ext_vector_type(4))) float f32x4;

static __device__ __forceinline__ unsigned short f2bf(float f) {
  __hip_bfloat16 h = __float2bfloat16(f);
  return *reinterpret_cast<unsigned short*>(&h);
}

#define CVT8(dst, va, vb) {                                                       \
    short8 _v;                                                                    \
    _v[0] = (short)f2bf((va).x); _v[1] = (short)f2bf((va).y);                     \
    _v[2] = (short)f2bf((va).z); _v[3] = (short)f2bf((va).w);                     \
    _v[4] = (short)f2bf((vb).x); _v[5] = (short)f2bf((vb).y);                     \
    _v[6] = (short)f2bf((vb).z); _v[7] = (short)f2bf((vb).w);                     \
    *reinterpret_cast<short8*>(dst) = _v; }

// Single kernel, no cross-block communication:
//  prologue (per block, redundant): k_d = Re(sum_n conj(c)b lam^d) for d in [0,703],
//  scattered as XOR-swizzled Toeplitz tiles kt[6][64][128] in LDS;
//  main loop: out-tile 64x64 = sum_j A_j(64x128 from u, reg-staged->LDS) * kt_j^T.
__global__ __launch_bounds__(256) void ssm_one(
    const float* __restrict__ u, const float* __restrict__ rho,
    const float* __restrict__ theta, const float* __restrict__ br,
    const float* __restrict__ bi, const float* __restrict__ cr,
    const float* __restrict__ ci, float* __restrict__ out) {
  __shared__ __align__(16) unsigned short kt_s[NLAG * 8192];   // 96 KB, resident B
  __shared__ __align__(16) unsigned short Ab[2][8192];         // 2 x 16 KB A dbuf
  __shared__ __align__(16) float4 mt[64];                      // per-mode params

  const int tid = threadIdx.x;
  const int lane = tid & 63;
  const int w = tid >> 6;
  const int wm = (w >> 1) & 1, wn = w & 1;

  const int bid = blockIdx.x;                // 256 % 8 == 0 -> bijective XCD swizzle
  const int swz = (bid & 7) * 32 + (bid >> 3);
  const int t0 = (swz & 63) * 64;
  const int b0 = (swz >> 6) * 64;

  const int lrow = lane >> 4, lc16 = lane & 15;
  const float4 z4 = make_float4(0.f, 0.f, 0.f, 0.f);
  float4 av[4][2];
  f32x4 acc[2][2] = {};

  // ---- issue A(0) global loads immediately (latency hides under prologue) ----
#define ISSUEA(j) { _Pragma("unroll") for (int h_ = 0; h_ < 4; ++h_) {            \
    const int hh = tid + 256 * h_;                                                \
    const int r_ = hh >> 4, cg = hh & 15;                                         \
    const int gg = t0 - (j) * 128 + cg * 8;       /* 8-aligned: no 4096-straddle */\
    if ((unsigned)gg < 4096u) {                                                   \
      const float* p_ = u + (size_t)(b0 + r_) * T_LEN + gg;                       \
      av[h_][0] = *reinterpret_cast<const float4*>(p_);                           \
      av[h_][1] = *reinterpret_cast<const float4*>(p_ + 4);                       \
    } else { av[h_][0] = z4; av[h_][1] = z4; } } }

#define WRITEA(buf) { _Pragma("unroll") for (int h_ = 0; h_ < 4; ++h_) {          \
    const int hh = tid + 256 * h_;                                                \
    const int r_ = hh >> 4, cg = hh & 15;                                         \
    const int eo = r_ * 128 + ((cg * 8) ^ ((r_ & 7) << 3));                       \
    CVT8(&Ab[buf][eo], av[h_][0], av[h_][1]); } }

  ISSUEA(0);

  // ---- prologue A: zero kt tiles (tile 0 needs zeros at d<0); build mode table --
  {
    const short8 z8 = {};
#pragma unroll
    for (int h = 0; h < 24; ++h)
      *reinterpret_cast<short8*>(&kt_s[(tid + 256 * h) * 8]) = z8;
    if (tid < 64) {
      const float lr2 = -1.4426950408f * log1pf(expf(rho[tid]));  // log2(r)
      mt[tid] = make_float4(lr2, theta[tid] * 0.15915494309f,     // theta/2pi
                            cr[tid] * br[tid] + ci[tid] * bi[tid],
                            cr[tid] * bi[tid] - ci[tid] * br[tid]);
    }
  }
  __syncthreads();

  // ---- prologue B: thread owns lags d = tid + 256p; compute k_d, scatter tiles --
#pragma unroll
  for (int p = 0; p < 3; ++p) {
    const int d = tid + 256 * p;
    if (d <= 703) {
      const float df = (float)d;
      float kd = 0.f;
#pragma unroll 8
      for (int n = 0; n < 64; ++n) {
        const float4 m4 = mt[n];
        const float rd = exp2f(df * m4.x);
        const float fr0 = df * m4.y;
        const float fr = fr0 - floorf(fr0);            // v_fract
        const float rad = 6.2831853072f * fr;
        const float sv = __sinf(rad), cv = __cosf(rad);
        kd = fmaf(rd, fmaf(-m4.w, sv, m4.z * cv), kd);
      }
      const unsigned short kv = f2bf(kd);
      const int q = d >> 7, m = d & 127;
      // per d exactly 64 tile entries; lane-staggered i2 spreads LDS banks
      if (m >= 64) {                                   // single tile q+1, all r
#pragma unroll 8
        for (int i = 0; i < 64; ++i) {
          const int i2 = (i + ((lane & 7) << 3)) & 63;
          const int r = i2, s = i2 + 128 - m;          // s in [128-m, 191-m]
          kt_s[(q + 1) * 8192 + r * 128 + (s ^ ((r & 7) << 3))] = kv;
        }
      } else {                                         // tiles q and (m>=1) q+1
#pragma unroll 8
        for (int i = 0; i < 64; ++i) {
          const int i2 = (i + ((lane & 7) << 3)) & 63;
          const int second = (i2 >= 64 - m) ? 1 : 0;
          const int jt = q + second;
          const int r = (m + i2) & 63;                 // no double-wrap for m<64
          const int s = i2 + (second ? 64 : 0);
          if (jt < NLAG)
            kt_s[jt * 8192 + r * 128 + (s ^ ((r & 7) << 3))] = kv;
        }
      }
    }
  }
  __syncthreads();          // kt complete & visible

  WRITEA(0);
  __syncthreads();          // Ab[0] ready

#define COMPUTE(jj, buf) {                                                        \
    const unsigned short* A  = Ab[buf];                                           \
    const unsigned short* Bt = kt_s + (jj) * 8192;                                \
    _Pragma("unroll") for (int ks = 0; ks < 4; ++ks) {                            \
      short8 af[2], bfr[2];                                                       \
      _Pragma("unroll") for (int ft = 0; ft < 2; ++ft) {                          \
        const int r = wm * 32 + ft * 16 + lc16;                                   \
        const int pe = (ks * 32 + lrow * 8) ^ ((r & 7) << 3);                     \
        af[ft] = *reinterpret_cast<const short8*>(&A[r * 128 + pe]); }            \
      _Pragma("unroll") for (int fn = 0; fn < 2; ++fn) {                          \
        const int r = wn * 32 + fn * 16 + lc16;                                   \
        const int pe = (ks * 32 + lrow * 8) ^ ((r & 7) << 3);                     \
        bfr[fn] = *reinterpret_cast<const short8*>(&Bt[r * 128 + pe]); }          \
      _Pragma("unroll") for (int ft = 0; ft < 2; ++ft)                            \
        _Pragma("unroll") for (int fn = 0; fn < 2; ++fn)                          \
          acc[ft][fn] = __builtin_amdgcn_mfma_f32_16x16x32_bf16(                  \
              af[ft], bfr[fn], acc[ft][fn], 0, 0, 0); } }

#pragma unroll
  for (int j = 0; j < NLAG; ++j) {
    if (j < NLAG - 1) ISSUEA(j + 1);       // loads fly over compute(j)
    COMPUTE(j, j & 1);
    if (j < NLAG - 1) {
      __syncthreads();                     // all waves done reading buf (j+1)&1
      WRITEA((j + 1) & 1);                 // waits on its own vmcnt only
      __syncthreads();                     // Ab[(j+1)&1] ready for compute(j+1)
    }
  }

  // ---- epilogue ----
#pragma unroll
  for (int ft = 0; ft < 2; ++ft)
#pragma unroll
    for (int fn = 0; fn < 2; ++fn)
#pragma unroll
      for (int rg = 0; rg < 4; ++rg) {
        const int row = b0 + wm * 32 + ft * 16 + lrow * 4 + rg;
        const int col = t0 + wn * 32 + fn * 16 + lc16;
        out[(size_t)row * T_LEN + col] = acc[ft][fn][rg];
      }
#undef ISSUEA
#undef WRITEA
#undef COMPUTE
}

extern "C" void kernel_launch(void* const* d_in, const int* in_sizes, int n_in,
                              void* d_out, int out_size, void* d_ws, size_t ws_size,
                              hipStream_t stream) {
  const float* u     = (const float*)d_in[0];
  const float* rho   = (const float*)d_in[1];
  const float* theta = (const float*)d_in[2];
  const float* br    = (const float*)d_in[3];
  const float* bi    = (const float*)d_in[4];
  const float* cr    = (const float*)d_in[5];
  const float* ci    = (const float*)d_in[6];
  float* out = (float*)d_out;

  ssm_one<<<256, 256, 0, stream>>>(u, rho, theta, br, bi, cr, ci, out);
}

// Round 7
// 15.754 us; speedup vs baseline: 5.1247x; 2.0489x over previous
//
#include <hip/hip_runtime.h>
#include <hip/hip_bf16.h>

#define T_LEN 4096
#define NLAG  6              // lags 0..703; absmax 2.0 validated (r5/r6)

typedef __attribute__((ext_vector_type(8))) short short8;
typedef __attribute__((ext_vector_type(4))) float f32x4;

static __device__ __forceinline__ unsigned short f2bf(float f) {
  __hip_bfloat16 h = __float2bfloat16(f);
  return *reinterpret_cast<unsigned short*>(&h);
}

#define CVT8(dst, va, vb) {                                                       \
    short8 _v;                                                                    \
    _v[0] = (short)f2bf((va).x); _v[1] = (short)f2bf((va).y);                     \
    _v[2] = (short)f2bf((va).z); _v[3] = (short)f2bf((va).w);                     \
    _v[4] = (short)f2bf((vb).x); _v[5] = (short)f2bf((vb).y);                     \
    _v[6] = (short)f2bf((vb).z); _v[7] = (short)f2bf((vb).w);                     \
    *reinterpret_cast<short8*>(dst) = _v; }

// Single launch. 512 threads: waves 0-3 GEMM consumers, waves 4-7 A-staging
// producers. Prologue (all 8 waves): k_d by per-mode complex recurrence
// (lane=mode, 4 FMA/lag, no transcendentals in the loop), transpose-reduced
// via a small LDS pad, then vector-scattered into swizzled Toeplitz tiles.
__global__ __launch_bounds__(512) void ssm_one(
    const float* __restrict__ u, const float* __restrict__ rho,
    const float* __restrict__ theta, const float* __restrict__ br,
    const float* __restrict__ bi, const float* __restrict__ cr,
    const float* __restrict__ ci, float* __restrict__ out) {
  __shared__ unsigned short kt_s[NLAG * 8192];              // 96 KB resident B
  __shared__ __align__(16) unsigned short Ab[2][8192];      // 32 KB A dbuf
  __shared__ float kl2[832];                                // k at [128+d], d<0 -> 0
  __shared__ __align__(16) float pad[8][8][68];             // per-wave reduce pad

  const int tid = threadIdx.x;
  const int lane = tid & 63;
  const int w = tid >> 6;                 // 0..7
  const bool prod = (w >= 4);
  const int pt = tid & 255;               // producer-local id

  const int bid = blockIdx.x;             // 256 % 8 == 0 -> bijective XCD swizzle
  const int swz = (bid & 7) * 32 + (bid >> 3);
  const int t0 = (swz & 63) * 64;
  const int b0 = (swz >> 6) * 64;

  const int lrow = lane >> 4, lc16 = lane & 15;
  const float4 z4 = make_float4(0.f, 0.f, 0.f, 0.f);
  float4 av[2][4][2];
  f32x4 acc[2][2] = {};

#define ISSUEA(j, S) { _Pragma("unroll") for (int h_ = 0; h_ < 4; ++h_) {         \
    const int hh = pt + 256 * h_;                                                 \
    const int r_ = hh >> 4, cg = hh & 15;                                         \
    const int gg = t0 - (j) * 128 + cg * 8;                                       \
    if ((unsigned)gg < 4096u) {                                                   \
      const float* p_ = u + (size_t)(b0 + r_) * T_LEN + gg;                       \
      av[S][h_][0] = *reinterpret_cast<const float4*>(p_);                        \
      av[S][h_][1] = *reinterpret_cast<const float4*>(p_ + 4);                    \
    } else { av[S][h_][0] = z4; av[S][h_][1] = z4; } } }

#define WRITEA(buf, S) { _Pragma("unroll") for (int h_ = 0; h_ < 4; ++h_) {       \
    const int hh = pt + 256 * h_;                                                 \
    const int r_ = hh >> 4, cg = hh & 15;                                         \
    const int eo = r_ * 128 + ((cg * 8) ^ ((r_ & 7) << 3));                       \
    CVT8(&Ab[buf][eo], av[S][h_][0], av[S][h_][1]); } }

  // ---- per-mode params (lane = mode) ----
  const float rh = rho[lane], th = theta[lane];
  const float lr2 = -1.4426950408f * log1pf(expf(rh));       // log2 r
  const float rr_ = exp2f(lr2);
  const float lre = rr_ * __cosf(th), lim = rr_ * __sinf(th);
  const float brv = br[lane], biv = bi[lane];
  const float crv = cr[lane], civ = ci[lane];
  const float wre = crv * brv + civ * biv;                   // conj(c)*b
  const float wim = crv * biv - civ * brv;

  if (prod) ISSUEA(0, 0);                 // A(0) HBM latency hides under prologue
  if (tid < 128) kl2[tid] = 0.f;          // d<0 zeros

  // ---- d-eval: wave w owns lags [88w, 88w+88); g = w*lam^d recurrence ----
  {
    const float d0f = (float)(88 * w);
    const float rd0 = exp2f(d0f * lr2);
    float f0 = d0f * (th * 0.15915494309f);
    f0 -= floorf(f0);
    const float a0 = 6.2831853072f * f0;
    const float c0 = __cosf(a0), s0 = __sinf(a0);
    float gr = rd0 * (wre * c0 - wim * s0);
    float gi = rd0 * (wre * s0 + wim * c0);

    float* mypad = &pad[w][0][0];
    const int rr2 = lane >> 3, cc = lane & 7;
    for (int rnd = 0; rnd < 11; ++rnd) {
#pragma unroll
      for (int i2 = 0; i2 < 8; ++i2) {
        mypad[i2 * 68 + lane] = gr;                 // bank: (4*i2+lane)&31, free
        const float ngr = gr * lre - gi * lim;
        const float ngi = gr * lim + gi * lre;
        gr = ngr; gi = ngi;
      }
      const float4 p0 = *reinterpret_cast<const float4*>(&mypad[rr2 * 68 + cc * 8]);
      const float4 p1 = *reinterpret_cast<const float4*>(&mypad[rr2 * 68 + cc * 8 + 4]);
      float s = ((p0.x + p0.y) + (p0.z + p0.w)) + ((p1.x + p1.y) + (p1.z + p1.w));
      s += __shfl_xor(s, 1); s += __shfl_xor(s, 2); s += __shfl_xor(s, 4);
      if (cc == 0) kl2[128 + 88 * w + rnd * 8 + rr2] = s;
    }
  }
  __syncthreads();                        // kl2 complete

  // ---- scatter: kt[j][r][s] = kl2[128 + j*128 + r - s], swizzled b128 writes ----
#pragma unroll
  for (int i = 0; i < 12; ++i) {
    const int g = w + 8 * i;              // (j, c8) plane; r = lane
    const int j = g >> 4, c8 = g & 15, r = lane;
    const int base = 128 + j * 128 + r - c8 * 8 - 7;   // in [1, 824]
    short8 o;
#pragma unroll
    for (int e = 0; e < 8; ++e) o[e] = (short)f2bf(kl2[base + 7 - e]);
    *reinterpret_cast<short8*>(
        &kt_s[j * 8192 + r * 128 + ((c8 * 8) ^ ((r & 7) << 3))]) = o;
  }

  if (prod) { WRITEA(0, 0); ISSUEA(1, 1); }
  __syncthreads();                        // kt_s + Ab[0] ready

#define COMPUTE(jj, buf) {                                                        \
    const unsigned short* A  = Ab[buf];                                           \
    const unsigned short* Bt = kt_s + (jj) * 8192;                                \
    const int wm = w >> 1, wn = w & 1;                                            \
    _Pragma("unroll") for (int ks = 0; ks < 4; ++ks) {                            \
      short8 af[2], bfr[2];                                                       \
      _Pragma("unroll") for (int ft = 0; ft < 2; ++ft) {                          \
        const int r = wm * 32 + ft * 16 + lc16;                                   \
        const int pe = (ks * 32 + lrow * 8) ^ ((r & 7) << 3);                     \
        af[ft] = *reinterpret_cast<const short8*>(&A[r * 128 + pe]); }            \
      _Pragma("unroll") for (int fn = 0; fn < 2; ++fn) {                          \
        const int r = wn * 32 + fn * 16 + lc16;                                   \
        const int pe = (ks * 32 + lrow * 8) ^ ((r & 7) << 3);                     \
        bfr[fn] = *reinterpret_cast<const short8*>(&Bt[r * 128 + pe]); }          \
      _Pragma("unroll") for (int ft = 0; ft < 2; ++ft)                            \
        _Pragma("unroll") for (int fn = 0; fn < 2; ++fn)                          \
          acc[ft][fn] = __builtin_amdgcn_mfma_f32_16x16x32_bf16(                  \
              af[ft], bfr[fn], acc[ft][fn], 0, 0, 0); } }

  // ---- pipeline: consumers compute buf j&1; producers fill buf (j+1)&1 ----
#pragma unroll
  for (int j = 0; j < NLAG; ++j) {
    if (prod) {
      if (j + 1 < NLAG) WRITEA((j + 1) & 1, (j + 1) & 1);
      if (j + 2 < NLAG) ISSUEA(j + 2, j & 1);
    } else {
      COMPUTE(j, j & 1);
    }
    __syncthreads();
  }

  // ---- epilogue (consumers only) ----
  if (!prod) {
    const int wm = w >> 1, wn = w & 1;
#pragma unroll
    for (int ft = 0; ft < 2; ++ft)
#pragma unroll
      for (int fn = 0; fn < 2; ++fn)
#pragma unroll
        for (int rg = 0; rg < 4; ++rg) {
          const int row = b0 + wm * 32 + ft * 16 + lrow * 4 + rg;
          const int col = t0 + wn * 32 + fn * 16 + lc16;
          out[(size_t)row * T_LEN + col] = acc[ft][fn][rg];
        }
  }
#undef ISSUEA
#undef WRITEA
#undef COMPUTE
}

extern "C" void kernel_launch(void* const* d_in, const int* in_sizes, int n_in,
                              void* d_out, int out_size, void* d_ws, size_t ws_size,
                              hipStream_t stream) {
  const float* u     = (const float*)d_in[0];
  const float* rho   = (const float*)d_in[1];
  const float* theta = (const float*)d_in[2];
  const float* br    = (const float*)d_in[3];
  const float* bi    = (const float*)d_in[4];
  const float* cr    = (const float*)d_in[5];
  const float* ci    = (const float*)d_in[6];
  float* out = (float*)d_out;

  ssm_one<<<256, 512, 0, stream>>>(u, rho, theta, br, bi, cr, ci, out);
}

// Round 8
// 13.264 us; speedup vs baseline: 6.0872x; 1.1878x over previous
//
#include <hip/hip_runtime.h>
#include <hip/hip_bf16.h>

#define T_LEN  4096
#define NLAG   5
#define CMAX   ((NLAG - 1) * 128 + 63)   // 575: max lag covered
#define ESTR   712                        // per-copy stride (bf16 elems), mult of 8
#define ROUNDS ((CMAX + 1) / 64)          // 9: lags per wave = 8*ROUNDS

typedef __attribute__((ext_vector_type(8))) short short8;
typedef __attribute__((ext_vector_type(4))) float f32x4;

static __device__ __forceinline__ unsigned short f2bf(float f) {
  __hip_bfloat16 h = __float2bfloat16(f);
  return *reinterpret_cast<unsigned short*>(&h);
}

#define CVT8(dst, va, vb) {                                                       \
    short8 _v;                                                                    \
    _v[0] = (short)f2bf((va).x); _v[1] = (short)f2bf((va).y);                     \
    _v[2] = (short)f2bf((va).z); _v[3] = (short)f2bf((va).w);                     \
    _v[4] = (short)f2bf((vb).x); _v[5] = (short)f2bf((vb).y);                     \
    _v[6] = (short)f2bf((vb).z); _v[7] = (short)f2bf((vb).w);                     \
    *reinterpret_cast<short8*>(dst) = _v; }

// Single launch. Waves 0-3: GEMM consumers; waves 4-7: A-staging producers.
// No Toeplitz tiles: B-fragments (8 consecutive-s elems of k_{j*128+r-s}) are
// 8 CONSECUTIVE entries of reversed-k E[y]=k_{CMAX-y}; 8 shifted bf16 copies
// A_p[x]=E[x+p] make every lane's ds_read_b128 16B-aligned (p=(CMAX-r)&7).
__global__ __launch_bounds__(512) void ssm_one(
    const float* __restrict__ u, const float* __restrict__ rho,
    const float* __restrict__ theta, const float* __restrict__ br,
    const float* __restrict__ bi, const float* __restrict__ cr,
    const float* __restrict__ ci, float* __restrict__ out) {
  __shared__ __align__(16) unsigned short Ab[2][8192];     // 32 KB A dbuf
  __shared__ __align__(16) unsigned short E8[8 * ESTR];    // 11.1 KB rev-k copies
  __shared__ __align__(16) float pad[8][8][68];            // 17.4 KB reduce pad

  const int tid = threadIdx.x;
  const int lane = tid & 63;
  const int w = tid >> 6;                 // 0..7
  const bool prod = (w >= 4);
  const int pt = tid & 255;

  const int bid = blockIdx.x;             // 256 % 8 == 0 -> bijective XCD swizzle
  const int swz = (bid & 7) * 32 + (bid >> 3);
  const int t0 = (swz & 63) * 64;
  const int b0 = (swz >> 6) * 64;

  const int lrow = lane >> 4, lc16 = lane & 15;
  const float4 z4 = make_float4(0.f, 0.f, 0.f, 0.f);
  float4 av[2][4][2];
  f32x4 acc[2][2] = {};

#define ISSUEA(j, S) { _Pragma("unroll") for (int h_ = 0; h_ < 4; ++h_) {         \
    const int hh = pt + 256 * h_;                                                 \
    const int r_ = hh >> 4, cg = hh & 15;                                         \
    const int gg = t0 - (j) * 128 + cg * 8;                                       \
    if ((unsigned)gg < 4096u) {                                                   \
      const float* p_ = u + (size_t)(b0 + r_) * T_LEN + gg;                       \
      av[S][h_][0] = *reinterpret_cast<const float4*>(p_);                        \
      av[S][h_][1] = *reinterpret_cast<const float4*>(p_ + 4);                    \
    } else { av[S][h_][0] = z4; av[S][h_][1] = z4; } } }

#define WRITEA(buf, S) { _Pragma("unroll") for (int h_ = 0; h_ < 4; ++h_) {       \
    const int hh = pt + 256 * h_;                                                 \
    const int r_ = hh >> 4, cg = hh & 15;                                         \
    const int eo = r_ * 128 + ((cg * 8) ^ ((r_ & 7) << 3));                       \
    CVT8(&Ab[buf][eo], av[S][h_][0], av[S][h_][1]); } }

  if (prod) ISSUEA(0, 0);                 // A(0) HBM latency hides under prologue

  // ---- zero E8 (tail y>CMAX must read 0) ----
  {
    const short8 z8 = {};
    for (int c = tid; c < ESTR; c += 512)
      *reinterpret_cast<short8*>(&E8[c * 8]) = z8;
  }

  // ---- per-mode params (lane = mode) + lambda powers ----
  const float rh = rho[lane], th = theta[lane];
  const float lr2 = -1.4426950408f * log1pf(expf(rh));       // log2 r
  const float rr_ = exp2f(lr2);
  const float lre = rr_ * __cosf(th), lim = rr_ * __sinf(th);
  const float brv = br[lane], biv = bi[lane];
  const float crv = cr[lane], civ = ci[lane];
  const float wre = crv * brv + civ * biv;                   // conj(c)*b
  const float wim = crv * biv - civ * brv;

  float Lr[9], Li[9];
  Lr[0] = 1.f; Li[0] = 0.f;
#pragma unroll
  for (int i = 1; i <= 8; ++i) {
    Lr[i] = Lr[i - 1] * lre - Li[i - 1] * lim;
    Li[i] = Lr[i - 1] * lim + Li[i - 1] * lre;
  }

  // g = conj(c)b * lam^d0, d0 = 8*ROUNDS*w
  const float d0f = (float)(8 * ROUNDS * w);
  const float rd0 = exp2f(d0f * lr2);
  float f0 = d0f * (th * 0.15915494309f);
  f0 -= floorf(f0);
  const float a0 = 6.2831853072f * f0;
  const float c0 = __cosf(a0), s0 = __sinf(a0);
  float gr = rd0 * (wre * c0 - wim * s0);
  float gi = rd0 * (wre * s0 + wim * c0);

  __syncthreads();                        // E8 zeros visible before stores

  // ---- d-eval: 8 independent products per round (ILP), 1 serial lam^8 step ----
  {
    float* mypad = &pad[w][0][0];
    const int r2 = lane >> 3, cc = lane & 7;
    for (int rnd = 0; rnd < ROUNDS; ++rnd) {
#pragma unroll
      for (int i2 = 0; i2 < 8; ++i2)
        mypad[i2 * 68 + lane] = gr * Lr[i2] - gi * Li[i2];   // Re(g * lam^i2)
      const float ngr = gr * Lr[8] - gi * Li[8];
      const float ngi = gr * Li[8] + gi * Lr[8];
      gr = ngr; gi = ngi;
      const float4 p0 = *reinterpret_cast<const float4*>(&mypad[r2 * 68 + cc * 8]);
      const float4 p1 = *reinterpret_cast<const float4*>(&mypad[r2 * 68 + cc * 8 + 4]);
      float s = ((p0.x + p0.y) + (p0.z + p0.w)) + ((p1.x + p1.y) + (p1.z + p1.w));
      s += __shfl_xor(s, 1); s += __shfl_xor(s, 2); s += __shfl_xor(s, 4);
      // lane (r2,cc) holds k_d, d = d0 + rnd*8 + r2; store copy p=cc at [y-cc]
      const int y = CMAX - (8 * ROUNDS * w + rnd * 8 + r2);
      if (y >= cc) E8[cc * ESTR + (y - cc)] = f2bf(s);
    }
  }

  if (prod) { WRITEA(0, 0); ISSUEA(1, 1); }
  __syncthreads();                        // E8 + Ab[0] ready

#define COMPUTE(jj, buf) {                                                        \
    const unsigned short* A = Ab[buf];                                            \
    const int wm = w >> 1, wn = w & 1;                                            \
    const int pB = 7 - (lc16 & 7);                                                \
    _Pragma("unroll") for (int ks = 0; ks < 4; ++ks) {                            \
      short8 af[2], bfr[2];                                                       \
      _Pragma("unroll") for (int ft = 0; ft < 2; ++ft) {                          \
        const int r = wm * 32 + ft * 16 + lc16;                                   \
        const int pe = (ks * 32 + lrow * 8) ^ ((r & 7) << 3);                     \
        af[ft] = *reinterpret_cast<const short8*>(&A[r * 128 + pe]); }            \
      _Pragma("unroll") for (int fn = 0; fn < 2; ++fn) {                          \
        const int rB = wn * 32 + fn * 16 + lc16;                                  \
        const int x0 = CMAX - (jj) * 128 - rB + ks * 32 + lrow * 8 - pB;          \
        bfr[fn] = *reinterpret_cast<const short8*>(&E8[pB * ESTR + x0]); }        \
      _Pragma("unroll") for (int ft = 0; ft < 2; ++ft)                            \
        _Pragma("unroll") for (int fn = 0; fn < 2; ++fn)                          \
          acc[ft][fn] = __builtin_amdgcn_mfma_f32_16x16x32_bf16(                  \
              af[ft], bfr[fn], acc[ft][fn], 0, 0, 0); } }

  // ---- pipeline: consumers compute buf j&1; producers fill buf (j+1)&1 ----
#pragma unroll
  for (int j = 0; j < NLAG; ++j) {
    if (prod) {
      if (j + 1 < NLAG) WRITEA((j + 1) & 1, (j + 1) & 1);
      if (j + 2 < NLAG) ISSUEA(j + 2, j & 1);
    } else {
      COMPUTE(j, j & 1);
    }
    if (j < NLAG - 1) __syncthreads();
  }

  // ---- epilogue (consumers only) ----
  if (!prod) {
    const int wm = w >> 1, wn = w & 1;
#pragma unroll
    for (int ft = 0; ft < 2; ++ft)
#pragma unroll
      for (int fn = 0; fn < 2; ++fn)
#pragma unroll
        for (int rg = 0; rg < 4; ++rg) {
          const int row = b0 + wm * 32 + ft * 16 + lrow * 4 + rg;
          const int col = t0 + wn * 32 + fn * 16 + lc16;
          out[(size_t)row * T_LEN + col] = acc[ft][fn][rg];
        }
  }
#undef ISSUEA
#undef WRITEA
#undef COMPUTE
}

extern "C" void kernel_launch(void* const* d_in, const int* in_sizes, int n_in,
                              void* d_out, int out_size, void* d_ws, size_t ws_size,
                              hipStream_t stream) {
  const float* u     = (const float*)d_in[0];
  const float* rho   = (const float*)d_in[1];
  const float* theta = (const float*)d_in[2];
  const float* br    = (const float*)d_in[3];
  const float* bi    = (const float*)d_in[4];
  const float* cr    = (const float*)d_in[5];
  const float* ci    = (const float*)d_in[6];
  float* out = (float*)d_out;

  ssm_one<<<256, 512, 0, stream>>>(u, rho, theta, br, bi, cr, ci, out);
}